// Round 2
// 786.734 us; speedup vs baseline: 1.0534x; 1.0534x over previous
//
#include <hip/hip_runtime.h>
#include <hip/hip_bf16.h>
#include <stdint.h>

#define IN_F   4096
#define OUT_F  11008
#define TOKENS 4096
#define NELEM_W ((size_t)OUT_F * (size_t)IN_F)   // 45,088,768
#define NELEM_X ((size_t)TOKENS * (size_t)IN_F)  // 16,777,216

// fallback tile
#define BM 128
#define BN 128
#define BK 32

// main GEMM tile (256^2 8-phase template)
#define BM2 256
#define BN2 256
#define BK2 64
#define NT2 (IN_F / BK2)   // 64 K-tiles

typedef __attribute__((ext_vector_type(8))) short short8;
typedef __attribute__((ext_vector_type(4))) float floatx4;

__device__ __forceinline__ void gload_lds16(const void* g, void* l) {
  __builtin_amdgcn_global_load_lds((const __attribute__((address_space(1))) void*)g,
                                   (__attribute__((address_space(3))) void*)l,
                                   16, 0, 0);
}

// round-to-nearest-even fp32 -> bf16 bit pattern
__device__ __forceinline__ ushort f2bf(float f) {
  union { float f; uint32_t u; } a; a.f = f;
  uint32_t u = a.u;
  return (ushort)((u + 0x7FFFu + ((u >> 16) & 1u)) >> 16);
}

// ternary quantization in fp64 (match float64 reference threshold semantics)
__device__ __forceinline__ ushort qtern(float v, double a) {
  double d = (double)v;
  return d > a ? (ushort)0x3F80 : (d < -a ? (ushort)0xBF80 : (ushort)0);
}

// ---------------- kernel 1: sum(|W|) in fp64 ----------------
__global__ __launch_bounds__(256) void absmean_reduce(const float* __restrict__ w,
                                                      double* __restrict__ out) {
  size_t tid = (size_t)blockIdx.x * 256 + threadIdx.x;
  size_t stride = (size_t)gridDim.x * 256;
  const float4* w4 = (const float4*)w;
  size_t n4 = NELEM_W / 4;
  double s0 = 0.0, s1 = 0.0, s2 = 0.0, s3 = 0.0;
  for (size_t i = tid; i < n4; i += stride) {
    float4 v = w4[i];
    s0 += (double)fabsf(v.x); s1 += (double)fabsf(v.y);
    s2 += (double)fabsf(v.z); s3 += (double)fabsf(v.w);
  }
  double s = (s0 + s1) + (s2 + s3);
#pragma unroll
  for (int off = 32; off > 0; off >>= 1) s += __shfl_down(s, off, 64);
  __shared__ double sm[4];
  int lane = threadIdx.x & 63, wv = threadIdx.x >> 6;
  if (lane == 0) sm[wv] = s;
  __syncthreads();
  if (threadIdx.x == 0) atomicAdd(out, (sm[0] + sm[1]) + (sm[2] + sm[3]));
}

// ---------------- kernel 2: x fp32 -> bf16 ----------------
__global__ __launch_bounds__(256) void convert_x(const float* __restrict__ x,
                                                 ushort* __restrict__ xb) {
  size_t i = ((size_t)blockIdx.x * 256 + threadIdx.x) * 8;
  float4 a = *(const float4*)(x + i);
  float4 b = *(const float4*)(x + i + 4);
  union { ushort s[8]; uint4 v; } u;
  u.s[0] = f2bf(a.x); u.s[1] = f2bf(a.y); u.s[2] = f2bf(a.z); u.s[3] = f2bf(a.w);
  u.s[4] = f2bf(b.x); u.s[5] = f2bf(b.y); u.s[6] = f2bf(b.z); u.s[7] = f2bf(b.w);
  *(uint4*)(xb + i) = u.v;
}

// ---------------- kernel 3: W fp32 -> ternary bf16 (+-1/0) ----------------
__global__ __launch_bounds__(256) void quantize_w(const float* __restrict__ w,
                                                  const double* __restrict__ asum,
                                                  ushort* __restrict__ wq) {
  double alpha = *asum * (1.0 / (double)NELEM_W);
  size_t i = ((size_t)blockIdx.x * 256 + threadIdx.x) * 8;
  float4 a = *(const float4*)(w + i);
  float4 b = *(const float4*)(w + i + 4);
  union { ushort s[8]; uint4 v; } u;
  u.s[0] = qtern(a.x, alpha); u.s[1] = qtern(a.y, alpha);
  u.s[2] = qtern(a.z, alpha); u.s[3] = qtern(a.w, alpha);
  u.s[4] = qtern(b.x, alpha); u.s[5] = qtern(b.y, alpha);
  u.s[6] = qtern(b.z, alpha); u.s[7] = qtern(b.w, alpha);
  *(uint4*)(wq + i) = u.v;
}

// ---------------- main GEMM: 256x256 tile, BK=64, 8 waves, phased schedule ----
// C[m][n] = sum_k A[m][k]*B[n][k], A/B bf16 row-major over k.
//
// LDS (128 KiB): As[2][256*64], Bs[2][256*64], 16B granules (row, c') with
// c' = c ^ (row&7): swizzle applied on the per-lane GLOBAL source (dst of
// global_load_lds is forced lane-contiguous, rule 21), un-applied on the
// ds_read_b128 fragment address -> conflict-free reads.
//
// Per K-tile t: 4 phases {ds_read subtile || issue 2 DMA -> barrier ->
// lgkmcnt(0) -> setprio(1) -> 16 MFMA -> setprio(0) -> barrier}.
//   phases 0-1 stage A(t+1) into As[base^1]  (dead since tile t-1)
//   phases 2-3 stage B(t+2) into Bs[base]    (B-frags fully read in phase 0)
// Tail: s_waitcnt vmcnt(4) -- retires A(t+1)+B(t+1-issued-last-tile), leaves
// B(t+2)'s 4 loads in flight. Never vmcnt(0) in the main loop (T4).
// Every barrier is bracketed by sched_barrier(0) so no ds_read/DMA/MFMA can
// migrate across a phase boundary (keeps positional vmcnt counting + region
// lifetimes valid under compiler motion; rule 18 insurance).
__device__ __forceinline__ void load_bf(short8 (&bf)[4][2], const ushort* bs,
                                        int brow, int cx0, int cx1) {
#pragma unroll
  for (int nf = 0; nf < 4; ++nf) {
    bf[nf][0] = *(const short8*)(bs + brow + nf * 1024 + cx0);
    bf[nf][1] = *(const short8*)(bs + brow + nf * 1024 + cx1);
  }
}

__device__ __forceinline__ void load_af(short8 (&af)[2][2], const ushort* as,
                                        int arow, int mf0, int cx0, int cx1) {
  af[0][0] = *(const short8*)(as + arow + (mf0 + 0) * 1024 + cx0);
  af[0][1] = *(const short8*)(as + arow + (mf0 + 0) * 1024 + cx1);
  af[1][0] = *(const short8*)(as + arow + (mf0 + 1) * 1024 + cx0);
  af[1][1] = *(const short8*)(as + arow + (mf0 + 1) * 1024 + cx1);
}

__device__ __forceinline__ void phase_mfma(floatx4 (&acc)[8][4],
                                           const short8 (&af)[2][2],
                                           const short8 (&bf)[4][2], int mf0) {
#pragma unroll
  for (int kk = 0; kk < 2; ++kk)
#pragma unroll
    for (int mi = 0; mi < 2; ++mi)
#pragma unroll
      for (int nf = 0; nf < 4; ++nf)
        acc[mf0 + mi][nf] = __builtin_amdgcn_mfma_f32_16x16x32_bf16(
            af[mi][kk], bf[nf][kk], acc[mf0 + mi][nf], 0, 0, 0);
}

__global__ __launch_bounds__(512, 2) void gemm_bt_bf16_256(
    const ushort* __restrict__ A, const ushort* __restrict__ B,
    const float* __restrict__ scale, const float* __restrict__ bias,
    float* __restrict__ C) {
  __shared__ __align__(16) ushort As[2][BM2 * BK2];  // 2 x 32 KiB
  __shared__ __align__(16) ushort Bs[2][BN2 * BK2];  // 2 x 32 KiB

  const int tid  = threadIdx.x;
  const int lane = tid & 63;
  const int wid  = tid >> 6;
  const int wm   = wid >> 2;   // 0..1  (128 rows each)
  const int wn   = wid & 3;    // 0..3  (64 cols each)
  const int quad = lane >> 4;
  const int r16  = lane & 15;

  const int row0 = blockIdx.x * BM2;  // x = m (fastest) for B-panel L2 sharing
  const int col0 = blockIdx.y * BN2;

  // per-lane pre-swizzled global staging sources: granule g = s*512 + tid,
  // row = g>>3, stored-col c' = g&7 holds global k-chunk c = c' ^ (row&7)
  const ushort* srcA[4];
  const ushort* srcB[4];
#pragma unroll
  for (int s = 0; s < 4; ++s) {
    int g = s * 512 + tid;
    int r = g >> 3;
    int c = (g & 7) ^ (r & 7);
    srcA[s] = A + (size_t)(row0 + r) * IN_F + c * 8;
    srcB[s] = B + (size_t)(col0 + r) * IN_F + c * 8;
  }

  // fragment read offsets: elem = row*64 + ((kk*4+quad) ^ (row&7))*8,
  // row&7 == r16&7 for all fragment rows
  const int cx0 = ((0 + quad) ^ (r16 & 7)) * 8;  // kk=0
  const int cx1 = ((4 + quad) ^ (r16 & 7)) * 8;  // kk=1
  const int arow = (wm * 128 + r16) * 64;
  const int brow = (wn * 64 + r16) * 64;

  floatx4 acc[8][4] = {};

#define STAGE_A2(b_, k_, s_) \
  gload_lds16(srcA[s_] + (k_), &As[b_][0] + ((s_) * 512 + wid * 64) * 8)
#define STAGE_B2(b_, k_, s_) \
  gload_lds16(srcB[s_] + (k_), &Bs[b_][0] + ((s_) * 512 + wid * 64) * 8)
#define SPIN() __builtin_amdgcn_sched_barrier(0)
#define MIDBAR()                                        \
  SPIN(); __builtin_amdgcn_s_barrier(); SPIN();         \
  asm volatile("s_waitcnt lgkmcnt(0)" ::: "memory");    \
  SPIN();                                               \
  __builtin_amdgcn_s_setprio(1)
#define ENDPHASE()                                      \
  __builtin_amdgcn_s_setprio(0);                        \
  SPIN(); __builtin_amdgcn_s_barrier(); SPIN()
#define VM4 asm volatile("s_waitcnt vmcnt(4)" ::: "memory")
#define VM0 asm volatile("s_waitcnt vmcnt(0)" ::: "memory")
#define VMNONE (void)0

#define TILE_BODY(BASE, t_, STA, STB, VMTAIL) do {                            \
    const ushort* as_ = &As[BASE][0];                                         \
    const ushort* bs_ = &Bs[BASE][0];                                         \
    const int kA_ = ((t_) + 1) * BK2;                                         \
    const int kB_ = ((t_) + 2) * BK2;                                         \
    short8 af[2][2]; short8 bf[4][2];                                         \
    /* phase 0 */                                                             \
    load_bf(bf, bs_, brow, cx0, cx1);                                         \
    load_af(af, as_, arow, 0, cx0, cx1);                                      \
    if (STA) { STAGE_A2(BASE ^ 1, kA_, 0); STAGE_A2(BASE ^ 1, kA_, 1); }      \
    MIDBAR(); phase_mfma(acc, af, bf, 0); ENDPHASE();                         \
    /* phase 1 */                                                             \
    load_af(af, as_, arow, 2, cx0, cx1);                                      \
    if (STA) { STAGE_A2(BASE ^ 1, kA_, 2); STAGE_A2(BASE ^ 1, kA_, 3); }      \
    MIDBAR(); phase_mfma(acc, af, bf, 2); ENDPHASE();                         \
    /* phase 2 */                                                             \
    load_af(af, as_, arow, 4, cx0, cx1);                                      \
    if (STB) { STAGE_B2(BASE, kB_, 0); STAGE_B2(BASE, kB_, 1); }              \
    MIDBAR(); phase_mfma(acc, af, bf, 4); ENDPHASE();                         \
    /* phase 3 */                                                             \
    load_af(af, as_, arow, 6, cx0, cx1);                                      \
    if (STB) { STAGE_B2(BASE, kB_, 2); STAGE_B2(BASE, kB_, 3); }              \
    MIDBAR(); phase_mfma(acc, af, bf, 6);                                     \
    __builtin_amdgcn_s_setprio(0);                                            \
    SPIN();                                                                   \
    VMTAIL;                                                                   \
    SPIN();                                                                   \
    __builtin_amdgcn_s_barrier();                                             \
    SPIN();                                                                   \
  } while (0)

  // prologue: B(0)+A(0) -> buf0, B(1) -> buf1; wait for tile 0 only
#pragma unroll
  for (int s = 0; s < 4; ++s) STAGE_B2(0, 0, s);
#pragma unroll
  for (int s = 0; s < 4; ++s) STAGE_A2(0, 0, s);
#pragma unroll
  for (int s = 0; s < 4; ++s) STAGE_B2(1, BK2, s);
  SPIN();
  VM4;
  SPIN();
  __builtin_amdgcn_s_barrier();
  SPIN();

  // main loop: explicit even/odd pair so buffer parity is a literal
  for (int t2 = 0; t2 < (NT2 - 2) / 2; ++t2) {  // 31 pairs -> t = 0..61
    const int t0 = 2 * t2;
    TILE_BODY(0, t0, 1, 1, VM4);
    TILE_BODY(1, t0 + 1, 1, 1, VM4);
  }
  TILE_BODY(0, NT2 - 2, 1, 0, VM0);   // t=62: stage A(63) only, drain all
  TILE_BODY(1, NT2 - 1, 0, 0, VMNONE);  // t=63: pure compute

#undef TILE_BODY
#undef MIDBAR
#undef ENDPHASE
#undef SPIN
#undef VM4
#undef VM0
#undef VMNONE
#undef STAGE_A2
#undef STAGE_B2

  // epilogue: C/D layout col = lane&15, row = quad*4 + reg
#pragma unroll
  for (int mf = 0; mf < 8; ++mf) {
    const int mbase = row0 + wm * 128 + mf * 16 + quad * 4;
#pragma unroll
    for (int nf = 0; nf < 4; ++nf) {
      const int n = col0 + wn * 64 + nf * 16 + r16;
      const float sc = scale[n];
      const float bi = bias[n];
      float* cp = C + (size_t)mbase * OUT_F + n;
#pragma unroll
      for (int r = 0; r < 4; ++r)
        cp[(size_t)r * OUT_F] = acc[mf][nf][r] * sc + bi;
    }
  }
}

// ---------------- fallback: fused fp32->bf16 quantize + GEMM (8B workspace) ----------------
__global__ __launch_bounds__(256) void gemm_fused_fp32(
    const float* __restrict__ X, const float* __restrict__ W,
    const double* __restrict__ asum,
    const float* __restrict__ scale, const float* __restrict__ bias,
    float* __restrict__ C) {
  __shared__ __align__(16) ushort As[BM * BK];
  __shared__ __align__(16) ushort Bs[BN * BK];
  const double alpha = *asum * (1.0 / (double)NELEM_W);

  const int tid  = threadIdx.x;
  const int lane = tid & 63;
  const int wid  = tid >> 6;
  const int wm   = wid & 1;
  const int wn   = wid >> 1;
  const int row0 = blockIdx.x * BM;
  const int col0 = blockIdx.y * BN;

  floatx4 acc[4][4] = {};
  const int quad = lane >> 4;
  const int r16  = lane & 15;

  for (int k0 = 0; k0 < IN_F; k0 += BK) {
    __syncthreads();
#pragma unroll
    for (int s = 0; s < 4; s++) {
      int g = tid + s * 256;
      int r = g >> 3, c = g & 7;
      float4 va = *(const float4*)(X + (size_t)(row0 + r) * IN_F + k0 + c * 4);
      ushort4 ua;
      ua.x = f2bf(va.x); ua.y = f2bf(va.y); ua.z = f2bf(va.z); ua.w = f2bf(va.w);
      *(ushort4*)(As + r * BK + c * 4) = ua;
      float4 vb = *(const float4*)(W + (size_t)(col0 + r) * IN_F + k0 + c * 4);
      ushort4 ub;
      ub.x = qtern(vb.x, alpha); ub.y = qtern(vb.y, alpha);
      ub.z = qtern(vb.z, alpha); ub.w = qtern(vb.w, alpha);
      *(ushort4*)(Bs + r * BK + c * 4) = ub;
    }
    __syncthreads();

    short8 af[4], bfr[4];
#pragma unroll
    for (int t = 0; t < 4; t++) {
      af[t]  = *(const short8*)(As + (wm * 64 + t * 16 + r16) * BK + quad * 8);
      bfr[t] = *(const short8*)(Bs + (wn * 64 + t * 16 + r16) * BK + quad * 8);
    }
#pragma unroll
    for (int i = 0; i < 4; i++)
#pragma unroll
      for (int j = 0; j < 4; j++)
        acc[i][j] = __builtin_amdgcn_mfma_f32_16x16x32_bf16(af[i], bfr[j], acc[i][j], 0, 0, 0);
  }

#pragma unroll
  for (int i = 0; i < 4; i++) {
    const int mbase = row0 + wm * 64 + i * 16 + quad * 4;
#pragma unroll
    for (int j = 0; j < 4; j++) {
      const int n = col0 + wn * 64 + j * 16 + r16;
      const float sc = scale[n];
      const float bi = bias[n];
      float* cp = C + (size_t)mbase * OUT_F + n;
#pragma unroll
      for (int r = 0; r < 4; r++)
        cp[(size_t)r * OUT_F] = acc[i][j][r] * sc + bi;
    }
  }
}

extern "C" void kernel_launch(void* const* d_in, const int* in_sizes, int n_in,
                              void* d_out, int out_size, void* d_ws, size_t ws_size,
                              hipStream_t stream) {
  const float* x     = (const float*)d_in[0];
  const float* w     = (const float*)d_in[1];
  const float* scale = (const float*)d_in[2];
  const float* bias  = (const float*)d_in[3];
  float* out = (float*)d_out;

  double* asum = (double*)d_ws;
  hipMemsetAsync(d_ws, 0, 8, stream);  // ws is re-poisoned 0xAA before every call
  absmean_reduce<<<2048, 256, 0, stream>>>(w, asum);

  const size_t offX = 64;
  const size_t offW = offX + NELEM_X * 2;
  const size_t need = offW + NELEM_W * 2;

  if (ws_size >= need) {
    ushort* xb = (ushort*)((char*)d_ws + offX);
    ushort* wb = (ushort*)((char*)d_ws + offW);
    convert_x<<<(int)(NELEM_X / 2048), 256, 0, stream>>>(x, xb);
    quantize_w<<<(int)(NELEM_W / 2048), 256, 0, stream>>>(w, asum, wb);
    dim3 grid2(TOKENS / BM2, OUT_F / BN2);  // 16 x 43
    gemm_bt_bf16_256<<<grid2, 512, 0, stream>>>(xb, wb, scale, bias, out);
  } else {
    dim3 grid(TOKENS / BM, OUT_F / BN);
    gemm_fused_fp32<<<grid, 256, 0, stream>>>(x, w, asum, scale, bias, out);
  }
}